// Round 1
// baseline (197.826 us; speedup 1.0000x reference)
//
#include <hip/hip_runtime.h>
#include <cstddef>

// Problem constants (from reference)
#define BB 64
#define NN 207
#define KK 32
#define CC 8
#define DIN 64
#define DOUT 64
#define TILE 8               // n-positions per block: 26x64=1664 blocks (6.5/CU vs 3.25 at TILE=16)
#define NT ((NN + TILE - 1) / TILE)   // 26 tiles along N
#define MPAD 68              // mean row stride: phase-2 class rows 4 banks apart

__device__ __forceinline__ float fast_tanh(float v) {
    // tanh(v) = 1 - 2/(exp(2v)+1); ~1e-6 rel err, saturates correctly.
    float e = __expf(2.0f * v);
    return 1.0f - 2.0f * __builtin_amdgcn_rcpf(e + 1.0f);
}

// ---- kernel 0: W[C][DOUT][DIN] -> Wt[C][DIN][DOUT] (one class per block) ----
__global__ __launch_bounds__(256) void transpose_W_kernel(
    const float* __restrict__ W, float* __restrict__ Wt)
{
    __shared__ float t[DIN * (DOUT + 1)];   // +1 pad: conflict-free transpose
    const int c   = blockIdx.x;
    const int tid = threadIdx.x;
    const float* __restrict__ Wc  = W  + (size_t)c * DOUT * DIN;
    float* __restrict__       Wtc = Wt + (size_t)c * DIN * DOUT;
    #pragma unroll
    for (int r = 0; r < 16; ++r) {
        const int i = r * 256 + tid;        // i = o*DIN + d  (coalesced read)
        const int o = i >> 6, d = i & 63;
        t[d * (DOUT + 1) + o] = Wc[i];
    }
    __syncthreads();
    #pragma unroll
    for (int r = 0; r < 16; ++r) {
        const int i = r * 256 + tid;        // i = d*DOUT + o (coalesced write)
        const int d = i >> 6, o = i & 63;
        Wtc[i] = t[d * (DOUT + 1) + o];
    }
}

// ---- main kernel ----
// TILE=8 layout:
//   phase 1: thread = (p = tid>>5 in 0..7, d2 = (tid&31)*2) -> float2 over all K=32.
//            16 loads in flight per batch (32 VGPR of data), acc[8] float2 = 16 VGPR.
//   phase 2: thread = (ph = tid>>7, c = (tid>>4)&7, o0 = (tid&15)*4) -> 4 positions.
template<bool USE_WT>
__global__ __launch_bounds__(256, 6) void ordered_gcn_kernel(
    const int* __restrict__ idx,      // [B, N, K]
    const float* __restrict__ x,      // [B, N, K, DIN]
    const float* __restrict__ W,      // [C, DOUT, DIN]
    const float* __restrict__ Wt,     // [C, DIN, DOUT] (in d_ws)
    float* __restrict__ out)          // [B, N, C, DOUT]
{
    __shared__ int   idx_s[TILE * KK];          // 1 KB
    __shared__ float inv_s[TILE * CC];          // 256 B
    __shared__ float mean_s[TILE * CC * MPAD];  // 17408 B  (total ~18.7 KB -> 8 blocks/CU by LDS)

    const int tid = threadIdx.x;
    const int b  = blockIdx.y;
    const int n0 = blockIdx.x * TILE;

    // ---- load idx tile: 256 ints, 1 per thread, coalesced ----
    {
        const int p = tid >> 5, k = tid & 31;
        int n = n0 + p; if (n > NN - 1) n = NN - 1;   // clamped rows never stored
        idx_s[tid] = idx[((size_t)(b * NN + n)) * KK + k];
    }
    __syncthreads();

    // ---- per (pos, class) inverse clamped count (64 threads) ----
    if (tid < TILE * CC) {
        const int pp = tid >> 3, c = tid & 7;
        int cnt = 0;
        #pragma unroll
        for (int k = 0; k < KK; ++k) cnt += (idx_s[pp * KK + k] == c) ? 1 : 0;
        inv_s[tid] = 1.0f / (float)(cnt > 1 ? cnt : 1);
    }
    // (inv_s is consumed only after the next barrier)

    // ---- phase 1: class-bucketed float2 sums, 16-deep load prefetch ----
    // Per load inst: lanes 0-31 = 256 B contiguous (pos p0, row k), lanes 32-63 = 256 B (pos p1).
    const int p  = tid >> 5;          // 0..7
    const int d2 = (tid & 31) * 2;    // 0..62
    {
        int n = n0 + p; if (n > NN - 1) n = NN - 1;
        const float* __restrict__ xp = x + ((size_t)(b * NN + n)) * KK * DIN + d2;

        float2 acc[CC];
        #pragma unroll
        for (int c = 0; c < CC; ++c) acc[c] = make_float2(0.f, 0.f);

        #pragma unroll 1   // two sequential batches: 16 loads in flight each
        for (int g = 0; g < 2; ++g) {
            float2 v[16];
            #pragma unroll
            for (int j = 0; j < 16; ++j)
                v[j] = *(const float2*)(xp + (size_t)(g * 16 + j) * DIN);
            #pragma unroll
            for (int j = 0; j < 16; ++j) {
                const int ca = idx_s[p * KK + g * 16 + j];
                #pragma unroll
                for (int cc_ = 0; cc_ < CC; ++cc_) {
                    const float mf = (ca == cc_) ? 1.0f : 0.0f;  // 1 cmp/sel + 2 fma per class
                    acc[cc_].x = fmaf(mf, v[j].x, acc[cc_].x);
                    acc[cc_].y = fmaf(mf, v[j].y, acc[cc_].y);
                }
            }
        }
        __syncthreads();   // inv_s ready for all threads

        #pragma unroll
        for (int cc_ = 0; cc_ < CC; ++cc_) {
            const float s = inv_s[p * CC + cc_];
            float2 m;
            m.x = acc[cc_].x * s; m.y = acc[cc_].y * s;
            *(float2*)(&mean_s[(p * CC + cc_) * MPAD + d2]) = m;
        }
    }
    __syncthreads();

    // ---- phase 2: out[p][c][o] = tanh(sum_d mean[p][c][d] * Wt[c][d][o]) ----
    // thread = (ph = tid>>7 -> pos 4ph..4ph+3, c = (tid>>4)&7, o0 = (tid&15)*4).
    // mean_s reads are 16-lane broadcasts; the 4 groups of a wave hit disjoint bank quads
    // (row stride MPAD=68 -> 4-bank offset per class row).
    {
        const int ph = tid >> 7;
        const int c  = (tid >> 4) & 7;
        const int o0 = (tid & 15) * 4;

        float4 acc2[4];
        #pragma unroll
        for (int pp = 0; pp < 4; ++pp) acc2[pp] = make_float4(0.f, 0.f, 0.f, 0.f);

        if (USE_WT) {
            const float* __restrict__ Wtc = Wt + (size_t)c * DIN * DOUT + o0;
            #pragma unroll 1
            for (int dc = 0; dc < 16; ++dc) {       // dd = dc*4
                const float4 w0 = *(const float4*)(Wtc + (size_t)(dc * 4 + 0) * DOUT);
                const float4 w1 = *(const float4*)(Wtc + (size_t)(dc * 4 + 1) * DOUT);
                const float4 w2 = *(const float4*)(Wtc + (size_t)(dc * 4 + 2) * DOUT);
                const float4 w3 = *(const float4*)(Wtc + (size_t)(dc * 4 + 3) * DOUT);
                #pragma unroll
                for (int pp = 0; pp < 4; ++pp) {
                    const int pq = ph * 4 + pp;
                    const float4 m = *(const float4*)(&mean_s[(pq * CC + c) * MPAD + dc * 4]);
                    acc2[pp].x = fmaf(m.x, w0.x, acc2[pp].x);
                    acc2[pp].y = fmaf(m.x, w0.y, acc2[pp].y);
                    acc2[pp].z = fmaf(m.x, w0.z, acc2[pp].z);
                    acc2[pp].w = fmaf(m.x, w0.w, acc2[pp].w);
                    acc2[pp].x = fmaf(m.y, w1.x, acc2[pp].x);
                    acc2[pp].y = fmaf(m.y, w1.y, acc2[pp].y);
                    acc2[pp].z = fmaf(m.y, w1.z, acc2[pp].z);
                    acc2[pp].w = fmaf(m.y, w1.w, acc2[pp].w);
                    acc2[pp].x = fmaf(m.z, w2.x, acc2[pp].x);
                    acc2[pp].y = fmaf(m.z, w2.y, acc2[pp].y);
                    acc2[pp].z = fmaf(m.z, w2.z, acc2[pp].z);
                    acc2[pp].w = fmaf(m.z, w2.w, acc2[pp].w);
                    acc2[pp].x = fmaf(m.w, w3.x, acc2[pp].x);
                    acc2[pp].y = fmaf(m.w, w3.y, acc2[pp].y);
                    acc2[pp].z = fmaf(m.w, w3.z, acc2[pp].z);
                    acc2[pp].w = fmaf(m.w, w3.w, acc2[pp].w);
                }
            }
        } else {
            // fallback: raw W layout (scattered within wave, works without d_ws)
            const float* __restrict__ Wc = W + (size_t)c * DOUT * DIN;
            #pragma unroll 1
            for (int dc = 0; dc < 16; ++dc) {
                float4 w[4];
                #pragma unroll
                for (int j = 0; j < 4; ++j)
                    w[j] = *(const float4*)(Wc + (size_t)(o0 + j) * DIN + dc * 4);
                #pragma unroll
                for (int pp = 0; pp < 4; ++pp) {
                    const int pq = ph * 4 + pp;
                    const float4 m = *(const float4*)(&mean_s[(pq * CC + c) * MPAD + dc * 4]);
                    float* a = (float*)&acc2[pp];
                    #pragma unroll
                    for (int j = 0; j < 4; ++j) {
                        a[j] = fmaf(m.x, w[j].x, a[j]);
                        a[j] = fmaf(m.y, w[j].y, a[j]);
                        a[j] = fmaf(m.z, w[j].z, a[j]);
                        a[j] = fmaf(m.w, w[j].w, a[j]);
                    }
                }
            }
        }

        #pragma unroll
        for (int pp = 0; pp < 4; ++pp) {
            const int pq = ph * 4 + pp;
            const int nn = n0 + pq;
            if (nn < NN) {
                float4 r;
                r.x = fast_tanh(acc2[pp].x);
                r.y = fast_tanh(acc2[pp].y);
                r.z = fast_tanh(acc2[pp].z);
                r.w = fast_tanh(acc2[pp].w);
                *(float4*)(out + (((size_t)(b * NN + nn)) * CC + c) * DOUT + o0) = r;
            }
        }
    }
}

extern "C" void kernel_launch(void* const* d_in, const int* in_sizes, int n_in,
                              void* d_out, int out_size, void* d_ws, size_t ws_size,
                              hipStream_t stream) {
    const int*   idx = (const int*)d_in[0];    // clustered_index_topk [B,N,K] int32
    const float* x   = (const float*)d_in[1];  // weightedDinput_topk [B,N,K,DIN] f32
    const float* W   = (const float*)d_in[2];  // W [C,DOUT,DIN] f32
    float* out = (float*)d_out;                // [B,N,C,DOUT] f32
    float* Wt  = (float*)d_ws;                 // [C,DIN,DOUT] scratch

    dim3 grid(NT, BB);   // 26 x 64 = 1664 blocks
    dim3 block(256);
    const size_t wt_bytes = (size_t)CC * DIN * DOUT * sizeof(float);  // 128 KB
    if (ws_size >= wt_bytes) {
        transpose_W_kernel<<<dim3(CC), block, 0, stream>>>(W, Wt);
        ordered_gcn_kernel<true><<<grid, block, 0, stream>>>(idx, x, W, Wt, out);
    } else {
        ordered_gcn_kernel<false><<<grid, block, 0, stream>>>(idx, x, W, Wt, out);
    }
}